// Round 13
// baseline (41.055 us; speedup 1.0000x reference)
//
#include <hip/hip_runtime.h>

#define B_ 8
#define C_ 64
#define H_ 192
#define W_ 320
#define HW_ (H_*W_)
#define OUT_ELEMS ((size_t)B_*C_*H_*W_)

#define CSPLIT 16           // channel chunks per batch
#define CPB    (C_/CSPLIT)  // 4 channels per block
#define PIXT   4            // pixels per thread (float4 store)
#define XTILES (HW_/(256*PIXT))        // 60 pixel-tiles per (b,chunk)
#define NWG    (XTILES * B_ * CSPLIT)  // 7680
#define NXCD   8

typedef float f32x4 __attribute__((ext_vector_type(4)));

// 8-byte tap-pair with only 4-byte alignment guarantee -> global_load_dwordx2.
struct __attribute__((packed, aligned(4))) fpair { float lo, hi; };

// Compute the 9 per-batch geometry params (f64). ~40 f64 ops + sin/cos.
__device__ inline void compute_params(const float* h_cam, const float* p_cam,
                                      const float* fu, const float* fv,
                                      const int* plane_h, int b, double* pp) {
    const double D  = 1e-16;
    const double cu = W_ / 2.0;   // 160
    const double cv = H_ / 2.0;   // 96
    double h   = (double)h_cam[b];
    double p   = (double)p_cam[b];
    double dfu = (double)fu[b];
    double dfv = (double)fv[b];
    double ph  = (double)plane_h[0];
    double h_ref = h - ph;
    double sp = sin(p), cp = cos(p);

    pp[0] = cu * cp;                       // m00
    pp[1] = -dfu;                          // m01
    pp[2] = cu * h_ref * sp;               // m02
    pp[3] = cv * cp - dfv * sp;            // m10
    pp[4] = h_ref * (dfv * cp + cv * sp);  // m12
    pp[5] = cp;                            // m20
    pp[6] = h_ref * sp;                    // m22
    pp[7] = h / (sp * (cv * cp + dfv * sp) + D);  // s
    pp[8] = h * cp / (sp + D);                    // cx
}

__global__ __launch_bounds__(256)
void bev_fused_kernel(const float* __restrict__ x,
                      const float* __restrict__ h_cam,
                      const float* __restrict__ p_cam,
                      const float* __restrict__ fu,
                      const float* __restrict__ fv,
                      const int*   __restrict__ plane_h,
                      float* __restrict__ out) {
    // XCD-aware bijective swizzle (T1).
    const int wg    = blockIdx.x;                      // 0..NWG-1
    const int newid = (wg % NXCD) * (NWG / NXCD) + (wg / NXCD);
    const int bc    = newid / XTILES;                  // 0..127
    const int xt    = newid - bc * XTILES;             // 0..59
    const int b     = bc >> 4;                         // CSPLIT = 16
    const int c0    = (bc & 15) * CPB;
    const int pix0  = (xt * 256 + threadIdx.x) * PIXT;
    const int v     = pix0 / W_;                       // 4 | W: all 4 px same row
    const int u     = pix0 - v * W_;

    // Per-block geometry: lane 0 computes, LDS broadcast.
    __shared__ double pps[9];
    if (threadIdx.x == 0) {
        double tmp[9];
        compute_params(h_cam, p_cam, fu, fv, plane_h, b, tmp);
        #pragma unroll
        for (int i = 0; i < 9; ++i) pps[i] = tmp[i];
    }
    // Block 0 also writes the scales (8) + centers (24) output tail.
    if (wg == 0 && threadIdx.x < B_) {
        double tmp[9];
        compute_params(h_cam, p_cam, fu, fv, plane_h, (int)threadIdx.x, tmp);
        float* scales_out  = out + OUT_ELEMS;
        float* centers_out = out + OUT_ELEMS + B_;
        scales_out[threadIdx.x] = (float)tmp[7];
        centers_out[threadIdx.x*3 + 0] = (float)tmp[8];
        centers_out[threadIdx.x*3 + 1] = 0.0f;
        centers_out[threadIdx.x*3 + 2] = 1.0f;
    }
    __syncthreads();

    const double m00 = pps[0], m01 = pps[1], m02 = pps[2];
    const double m10 = pps[3], m12 = pps[4];
    const double m20 = pps[5], m22 = pps[6];
    const double s   = pps[7], cx  = pps[8];

    // Row-level geometry: t2 and sv depend only on v; su is affine in u.
    const double wx     = cx + s * ((double)(H_/2) - (double)v);
    const double t2     = m20 * wx + m22;
    const double inv_t2 = 1.0 / t2;
    const double sv     = (m10 * wx + m12) * inv_t2;
    const double su_c   = (m00 * wx + m02) * inv_t2;   // constant part
    const double su_k   = m01 * s * inv_t2;            // coeff of (cu - u)

    const bool rowin = (sv >= 0.0) && (sv < (double)(H_-1));
    int v0i = 0;
    float dv0 = 0.f, dv1 = 0.f;
    if (rowin) {
        v0i = (int)sv;                          // sv >= 0
        dv0 = (float)(sv - (double)v0i);
        dv1 = (float)((double)(v0i + 1) - sv);
    }

    float wa[PIXT], wb[PIXT], wc[PIXT], wd[PIXT];
    int   base[PIXT];
    #pragma unroll
    for (int k = 0; k < PIXT; ++k) {
        const double su = su_c + su_k * ((double)(W_/2) - (double)(u + k));
        const bool inr = rowin && (su >= 0.0) && (su < (double)(W_-1));
        int u0i = 0;
        float du0 = 0.f, du1 = 0.f;
        if (inr) {
            u0i = (int)su;
            du0 = (float)(su - (double)u0i);
            du1 = (float)((double)(u0i + 1) - su);
        }
        wa[k] = dv1 * du1;   // (v0, u0)
        wb[k] = dv0 * du1;   // (v1, u0)
        wc[k] = dv1 * du0;   // (v0, u1)
        wd[k] = dv0 * du0;   // (v1, u1)
        base[k] = v0i * W_ + u0i;
    }

    const float* __restrict__ xb = x   + ((size_t)(b * C_ + c0)) * HW_;
    float* __restrict__       ob = out + ((size_t)(b * C_ + c0)) * HW_ + (size_t)pix0;

    // 4 channels: issue all 32 tap-pair gathers, then combine + PLAIN store
    // (A/B vs nontemporal: NT bypasses L2 write-combining; fill-buffer's
    // 7 TB/s write rate is achieved with normal stores).
    fpair tp[CPB][PIXT], bp[CPB][PIXT];
    #pragma unroll
    for (int c = 0; c < CPB; ++c) {
        const float* __restrict__ xc = xb + (size_t)c * HW_;
        #pragma unroll
        for (int k = 0; k < PIXT; ++k) {
            tp[c][k] = *(const fpair*)(xc + base[k]);        // (v0,u0),(v0,u1)
            bp[c][k] = *(const fpair*)(xc + base[k] + W_);   // (v1,u0),(v1,u1)
        }
    }
    #pragma unroll
    for (int c = 0; c < CPB; ++c) {
        f32x4 r;
        r.x = wa[0]*tp[c][0].lo + wc[0]*tp[c][0].hi + wb[0]*bp[c][0].lo + wd[0]*bp[c][0].hi;
        r.y = wa[1]*tp[c][1].lo + wc[1]*tp[c][1].hi + wb[1]*bp[c][1].lo + wd[1]*bp[c][1].hi;
        r.z = wa[2]*tp[c][2].lo + wc[2]*tp[c][2].hi + wb[2]*bp[c][2].lo + wd[2]*bp[c][2].hi;
        r.w = wa[3]*tp[c][3].lo + wc[3]*tp[c][3].hi + wb[3]*bp[c][3].lo + wd[3]*bp[c][3].hi;
        *(f32x4*)(ob + (size_t)c * HW_) = r;
    }
}

extern "C" void kernel_launch(void* const* d_in, const int* in_sizes, int n_in,
                              void* d_out, int out_size, void* d_ws, size_t ws_size,
                              hipStream_t stream) {
    const float* x     = (const float*)d_in[0];
    const float* h_cam = (const float*)d_in[1];
    const float* p_cam = (const float*)d_in[2];
    const float* fu    = (const float*)d_in[3];
    const float* fv    = (const float*)d_in[4];
    const int*   ph    = (const int*)  d_in[5];

    bev_fused_kernel<<<NWG, 256, 0, stream>>>(x, h_cam, p_cam, fu, fv, ph,
                                              (float*)d_out);
}

// Round 14
// 40.117 us; speedup vs baseline: 1.0234x; 1.0234x over previous
//
#include <hip/hip_runtime.h>

#define B_ 8
#define C_ 64
#define H_ 192
#define W_ 320
#define HW_ (H_*W_)
#define OUT_ELEMS ((size_t)B_*C_*H_*W_)

#define CSPLIT 16           // channel chunks per batch
#define CPB    (C_/CSPLIT)  // 4 channels per block
#define PIXT   4            // pixels per thread (float4 store)
#define XTILES (HW_/(256*PIXT))        // 60 pixel-tiles per (b,chunk)
#define NWG    (XTILES * B_ * CSPLIT)  // 7680
#define NXCD   8

typedef float f32x4 __attribute__((ext_vector_type(4)));

// 8-byte tap-pair with only 4-byte alignment guarantee -> global_load_dwordx2.
struct __attribute__((packed, aligned(4))) fpair { float lo, hi; };

// Compute the 9 per-batch geometry params (f64). ~40 f64 ops + sin/cos.
__device__ inline void compute_params(const float* h_cam, const float* p_cam,
                                      const float* fu, const float* fv,
                                      const int* plane_h, int b, double* pp) {
    const double D  = 1e-16;
    const double cu = W_ / 2.0;   // 160
    const double cv = H_ / 2.0;   // 96
    double h   = (double)h_cam[b];
    double p   = (double)p_cam[b];
    double dfu = (double)fu[b];
    double dfv = (double)fv[b];
    double ph  = (double)plane_h[0];
    double h_ref = h - ph;
    double sp = sin(p), cp = cos(p);

    pp[0] = cu * cp;                       // m00
    pp[1] = -dfu;                          // m01
    pp[2] = cu * h_ref * sp;               // m02
    pp[3] = cv * cp - dfv * sp;            // m10
    pp[4] = h_ref * (dfv * cp + cv * sp);  // m12
    pp[5] = cp;                            // m20
    pp[6] = h_ref * sp;                    // m22
    pp[7] = h / (sp * (cv * cp + dfv * sp) + D);  // s
    pp[8] = h * cp / (sp + D);                    // cx
}

__global__ __launch_bounds__(256)
void bev_fused_kernel(const float* __restrict__ x,
                      const float* __restrict__ h_cam,
                      const float* __restrict__ p_cam,
                      const float* __restrict__ fu,
                      const float* __restrict__ fv,
                      const int*   __restrict__ plane_h,
                      float* __restrict__ out) {
    // XCD-aware bijective swizzle (T1).
    const int wg    = blockIdx.x;                      // 0..NWG-1
    const int newid = (wg % NXCD) * (NWG / NXCD) + (wg / NXCD);
    const int bc    = newid / XTILES;                  // 0..127
    const int xt    = newid - bc * XTILES;             // 0..59
    const int b     = bc >> 4;                         // CSPLIT = 16
    const int c0    = (bc & 15) * CPB;
    const int pix0  = (xt * 256 + threadIdx.x) * PIXT;
    const int v     = pix0 / W_;                       // 4 | W: all 4 px same row
    const int u     = pix0 - v * W_;

    // Per-block geometry: lane 0 computes, LDS broadcast.
    __shared__ double pps[9];
    if (threadIdx.x == 0) {
        double tmp[9];
        compute_params(h_cam, p_cam, fu, fv, plane_h, b, tmp);
        #pragma unroll
        for (int i = 0; i < 9; ++i) pps[i] = tmp[i];
    }
    // Block 0 also writes the scales (8) + centers (24) output tail.
    if (wg == 0 && threadIdx.x < B_) {
        double tmp[9];
        compute_params(h_cam, p_cam, fu, fv, plane_h, (int)threadIdx.x, tmp);
        float* scales_out  = out + OUT_ELEMS;
        float* centers_out = out + OUT_ELEMS + B_;
        scales_out[threadIdx.x] = (float)tmp[7];
        centers_out[threadIdx.x*3 + 0] = (float)tmp[8];
        centers_out[threadIdx.x*3 + 1] = 0.0f;
        centers_out[threadIdx.x*3 + 2] = 1.0f;
    }
    __syncthreads();

    const double m00 = pps[0], m01 = pps[1], m02 = pps[2];
    const double m10 = pps[3], m12 = pps[4];
    const double m20 = pps[5], m22 = pps[6];
    const double s   = pps[7], cx  = pps[8];

    // Row-level geometry: t2 and sv depend only on v; su is affine in u.
    const double wx     = cx + s * ((double)(H_/2) - (double)v);
    const double t2     = m20 * wx + m22;
    const double inv_t2 = 1.0 / t2;
    const double sv     = (m10 * wx + m12) * inv_t2;
    const double su_c   = (m00 * wx + m02) * inv_t2;   // constant part
    const double su_k   = m01 * s * inv_t2;            // coeff of (cu - u)

    const bool rowin = (sv >= 0.0) && (sv < (double)(H_-1));
    int v0i = 0;
    float dv0 = 0.f, dv1 = 0.f;
    if (rowin) {
        v0i = (int)sv;                          // sv >= 0
        dv0 = (float)(sv - (double)v0i);
        dv1 = (float)((double)(v0i + 1) - sv);
    }

    float wa[PIXT], wb[PIXT], wc[PIXT], wd[PIXT];
    int   base[PIXT];
    #pragma unroll
    for (int k = 0; k < PIXT; ++k) {
        const double su = su_c + su_k * ((double)(W_/2) - (double)(u + k));
        const bool inr = rowin && (su >= 0.0) && (su < (double)(W_-1));
        int u0i = 0;
        float du0 = 0.f, du1 = 0.f;
        if (inr) {
            u0i = (int)su;
            du0 = (float)(su - (double)u0i);
            du1 = (float)((double)(u0i + 1) - su);
        }
        wa[k] = dv1 * du1;   // (v0, u0)
        wb[k] = dv0 * du1;   // (v1, u0)
        wc[k] = dv1 * du0;   // (v0, u1)
        wd[k] = dv0 * du0;   // (v1, u1)
        base[k] = v0i * W_ + u0i;
    }

    const float* __restrict__ xb = x   + ((size_t)(b * C_ + c0)) * HW_;
    float* __restrict__       ob = out + ((size_t)(b * C_ + c0)) * HW_ + (size_t)pix0;

    // 4 channels: issue all 32 tap-pair gathers, then combine + NT store.
    fpair tp[CPB][PIXT], bp[CPB][PIXT];
    #pragma unroll
    for (int c = 0; c < CPB; ++c) {
        const float* __restrict__ xc = xb + (size_t)c * HW_;
        #pragma unroll
        for (int k = 0; k < PIXT; ++k) {
            tp[c][k] = *(const fpair*)(xc + base[k]);        // (v0,u0),(v0,u1)
            bp[c][k] = *(const fpair*)(xc + base[k] + W_);   // (v1,u0),(v1,u1)
        }
    }
    #pragma unroll
    for (int c = 0; c < CPB; ++c) {
        f32x4 r;
        r.x = wa[0]*tp[c][0].lo + wc[0]*tp[c][0].hi + wb[0]*bp[c][0].lo + wd[0]*bp[c][0].hi;
        r.y = wa[1]*tp[c][1].lo + wc[1]*tp[c][1].hi + wb[1]*bp[c][1].lo + wd[1]*bp[c][1].hi;
        r.z = wa[2]*tp[c][2].lo + wc[2]*tp[c][2].hi + wb[2]*bp[c][2].lo + wd[2]*bp[c][2].hi;
        r.w = wa[3]*tp[c][3].lo + wc[3]*tp[c][3].hi + wb[3]*bp[c][3].lo + wd[3]*bp[c][3].hi;
        __builtin_nontemporal_store(r, (f32x4*)(ob + (size_t)c * HW_));
    }
}

extern "C" void kernel_launch(void* const* d_in, const int* in_sizes, int n_in,
                              void* d_out, int out_size, void* d_ws, size_t ws_size,
                              hipStream_t stream) {
    const float* x     = (const float*)d_in[0];
    const float* h_cam = (const float*)d_in[1];
    const float* p_cam = (const float*)d_in[2];
    const float* fu    = (const float*)d_in[3];
    const float* fv    = (const float*)d_in[4];
    const int*   ph    = (const int*)  d_in[5];

    bev_fused_kernel<<<NWG, 256, 0, stream>>>(x, h_cam, p_cam, fu, fv, ph,
                                              (float*)d_out);
}